// Round 11
// baseline (161.147 us; speedup 1.0000x reference)
//
#include <hip/hip_runtime.h>
#include <stdint.h>

// Problem: out[m][n] = sum_k x[m][k] * w[n][k] + bias[n]
//   M=256, N=16384, K=4096, w = dequant(2-bit, group=16 along k)
// Round 11: deepen the round-10 producer/consumer win (62us).
//  - consumers now 64m x 32n (wm=w>>1, wn=w&1): each reads only its n-half
//    of B -> consumer LDS reads halved (block LDS traffic 40->24 KB/body).
//  - 4-deep LDS buffer (32 KiB), barrier every 2 tiles: 32 barriers not 64.
//    Phase parity: consumers read bufs {0,1} while producers write {2,3},
//    then swap.
//  - A reg-prefetch at chunk (32-k) granularity, ping-pong 4+4 uint4
//    (keeps consumer VGPR ~90); producers hold 2 tile-pairs in flight
//    (qE/qO, 2-phase lead on the q2 HBM stream).
// Skeleton unchanged: grid (256,2), 512 thr, BM=128/BN=64/BK=64, XOR-swizzled
// B LDS, lgkm-only barrier, A via coalesced fragment workspace, setprio(1)
// around MFMA clusters.
#define M_DIM 256
#define N_DIM 16384
#define K_DIM 4096
#define BN 64
#define BK 64
#define NT (K_DIM / BK)   // 64 k-tiles

typedef __bf16 bf16x8 __attribute__((ext_vector_type(8)));
typedef float  f32x4  __attribute__((ext_vector_type(4)));

// fp32 -> bf16 bits, round-nearest-even (finite inputs)
__device__ __forceinline__ uint32_t f2bf(float f) {
  uint32_t u = __float_as_uint(f);
  return (u + 0x7fffu + ((u >> 16) & 1u)) >> 16;
}

// Barrier that waits ONLY on LDS ops -- global prefetches stay in flight.
#define LDS_BARRIER() \
  asm volatile("s_waitcnt lgkmcnt(0)\n\ts_barrier" ::: "memory")

// ---------------------------------------------------------------------------
// Kernel 1: x fp32 [256][4096] -> bf16 fragment-chunk order (unchanged).
// Chunk = (m-block of 16 rows) x (k-chunk of 32): 64 slots x 16B.
// Slot L holds row (L&15), k = (L>>4)*8 .. +7  (MFMA 16x16x32 A-frag order).
// ws uint4 index = (mb_glob*128 + kch)*64 + L.
// ---------------------------------------------------------------------------
__global__ __launch_bounds__(256) void cvt_x_kernel(const float* __restrict__ x,
                                                    uint4* __restrict__ ws) {
  int T = blockIdx.x * 256 + threadIdx.x;       // 0..131071
  int mb_glob = T >> 13;                        // 16 m-blocks
  int r       = T & 8191;
  int kch     = r >> 6;                         // 128 k-chunks
  int L       = r & 63;
  int row = mb_glob * 16 + (L & 15);
  int k   = kch * 32 + (L >> 4) * 8;
  const float* p = x + (size_t)row * K_DIM + k;
  float4 a = *(const float4*)p;
  float4 b = *(const float4*)(p + 4);
  uint4 o;
  o.x = f2bf(a.x) | (f2bf(a.y) << 16);
  o.y = f2bf(a.z) | (f2bf(a.w) << 16);
  o.z = f2bf(b.x) | (f2bf(b.y) << 16);
  o.w = f2bf(b.z) | (f2bf(b.w) << 16);
  ws[T] = o;
}

// ---------------------------------------------------------------------------
// Dequant 8 elems (2 packed q2 words; 4 crumbs in each low byte) of one group.
// Table entries {-n, a-n, 2a-n, 3a-n}, a = n*2/3 -- bit-identical to the
// fmaf+f2bf reference path.  v_perm_b32 picks the bf16 entry per crumb.
// ---------------------------------------------------------------------------
__device__ __forceinline__ uint4 deq8(uint32_t qx, uint32_t qy, uint32_t tlo,
                                      uint32_t thi) {
  uint32_t s0 = ((qx & 3u) | ((qx & 0xCu) << 14)) * 0x0202u + 0x01000100u;
  uint32_t s1 = (((qx >> 4) & 3u) | ((qx & 0xC0u) << 10)) * 0x0202u + 0x01000100u;
  uint32_t s2 = ((qy & 3u) | ((qy & 0xCu) << 14)) * 0x0202u + 0x01000100u;
  uint32_t s3 = (((qy >> 4) & 3u) | ((qy & 0xC0u) << 10)) * 0x0202u + 0x01000100u;
  uint4 r;
  r.x = __builtin_amdgcn_perm(thi, tlo, s0);
  r.y = __builtin_amdgcn_perm(thi, tlo, s1);
  r.z = __builtin_amdgcn_perm(thi, tlo, s2);
  r.w = __builtin_amdgcn_perm(thi, tlo, s3);
  return r;
}

// ---------------------------------------------------------------------------
// Kernel 2: grid (256,2), 512 threads, 8 waves: 4 consumers + 4 producers.
// LDS: Bb[4][512] -- tile T lives in buffer T&3 (8 chunks x 64 slots each).
// ---------------------------------------------------------------------------
__global__ __launch_bounds__(512, 4) void gemm2bit_kernel(
    const uint4*    __restrict__ aws,  // A chunks (see cvt)
    const uint32_t* __restrict__ q2,   // [G][4] packed 2-bit (low byte crumbs)
    const float*    __restrict__ nrm,  // [G] group norms (f32)
    const float*    __restrict__ bias, // [N]
    float*          __restrict__ out)  // [256][16384] fp32
{
  __shared__ uint4 Bb[4][512];  // 4-deep tile ring, 32 KiB

  const int tid  = threadIdx.x;
  const int lane = tid & 63;
  const int w    = tid >> 6;    // 0..7
  const int lo4  = lane & 15;
  const int qd   = lane >> 4;
  const int n0   = blockIdx.x * BN;
  const int m0   = blockIdx.y * 128;

  if (w < 4) {
    // ================== CONSUMER wave: 64m x 32n ==========================
    const int wm  = w >> 1;      // m-panel: rows m0 + wm*64 .. +63
    const int wn  = w & 1;       // n-half:  cols n0 + wn*32 .. +31
    const int lrs = lane ^ qd;   // swizzled read lane

    // A frag source: m-chunk mb = blockIdx.y*8 + wm*4 + s (s=0..3)
    const uint4* pA = aws + (size_t)(blockIdx.y * 8 + wm * 4) * 8192 + lane;

    f32x4 acc[4][2];
#pragma unroll
    for (int s = 0; s < 4; ++s)
#pragma unroll
      for (int u = 0; u < 2; ++u)
        acc[s][u] = (f32x4){0.f, 0.f, 0.f, 0.f};

    uint4 afE[4], afO[4];        // one k-chunk (32k) per set, ping-pong
#pragma unroll
    for (int s = 0; s < 4; ++s) afE[s] = pA[(size_t)s * 8192];  // chunk 0
    const uint4* pAp = pA + 64;  // next chunk to load
    int cnext = 1;               // chunk index of next load (0..128)
    LDS_BARRIER();

    // one chunk-step: prefetch A(cnext), 2 ds_read B, 8 MFMA
#define CONS_STEP(BUF, TS, AFC, AFN)                                            \
    do {                                                                        \
      if (cnext < 128) {                                                        \
        _Pragma("unroll")                                                       \
        for (int s = 0; s < 4; ++s) AFN[s] = pAp[(size_t)s * 8192];             \
      }                                                                         \
      pAp += 64; ++cnext;                                                       \
      __builtin_amdgcn_s_setprio(1);                                            \
      bf16x8 bv0 = *(const bf16x8*)&Bb[BUF][((TS) * 4 + wn * 2) * 64 + lrs];    \
      bf16x8 bv1 = *(const bf16x8*)&Bb[BUF][((TS) * 4 + wn * 2 + 1) * 64 + lrs];\
      _Pragma("unroll")                                                         \
      for (int s = 0; s < 4; ++s) {                                             \
        bf16x8 av = __builtin_bit_cast(bf16x8, AFC[s]);                         \
        acc[s][0] = __builtin_amdgcn_mfma_f32_16x16x32_bf16(av, bv0,            \
                                                            acc[s][0], 0, 0, 0);\
        acc[s][1] = __builtin_amdgcn_mfma_f32_16x16x32_bf16(av, bv1,            \
                                                            acc[s][1], 0, 0, 0);\
      }                                                                         \
      __builtin_amdgcn_s_setprio(0);                                            \
    } while (0)

    for (int tp = 0; tp < NT; tp += 4) {
      // even phase: tiles tp, tp+1 in bufs 0,1
      CONS_STEP(0, 0, afE, afO);
      CONS_STEP(0, 1, afO, afE);
      CONS_STEP(1, 0, afE, afO);
      CONS_STEP(1, 1, afO, afE);
      LDS_BARRIER();
      // odd phase: tiles tp+2, tp+3 in bufs 2,3
      CONS_STEP(2, 0, afE, afO);
      CONS_STEP(2, 1, afO, afE);
      CONS_STEP(3, 0, afE, afO);
      CONS_STEP(3, 1, afO, afE);
      LDS_BARRIER();
    }
#undef CONS_STEP

    // epilogue: C/D layout col=lane&15 (n), row=(lane>>4)*4+reg (m)
    float bv[2];
#pragma unroll
    for (int u = 0; u < 2; ++u)
      bv[u] = bias[n0 + wn * 32 + u * 16 + lo4];
#pragma unroll
    for (int s = 0; s < 4; ++s) {
      int mrow = m0 + wm * 64 + s * 16 + qd * 4;
#pragma unroll
      for (int u = 0; u < 2; ++u) {
        int ncol = n0 + wn * 32 + u * 16 + lo4;
        float* p = out + (size_t)mrow * N_DIM + ncol;
#pragma unroll
        for (int r = 0; r < 4; ++r)
          p[(size_t)r * N_DIM] = acc[s][u][r] + bv[u];
      }
    }
  } else {
    // ================== PRODUCER wave: 16n x 4 k-groups ===================
    const int pw    = w - 4;        // n-16-block 0..3
    const int kg    = lane & 3;     // k-group within BK (0..3)
    const int n_loc = lane >> 2;    // 0..15
    const int grow  = n0 + pw * 16 + n_loc;
    const int qd2a  = (kg & 1) * 2;
    const int qd2b  = qd2a + 1;
    const int bsA = ((kg >> 1) * 4 + pw) * 64 + qd2a * 16 + (n_loc ^ qd2a);
    const int bsB = ((kg >> 1) * 4 + pw) * 64 + qd2b * 16 + (n_loc ^ qd2b);

    const uint32_t* pq = q2 + ((size_t)grow * 256 + kg) * 4;  // +16 words/tile
    const float*    pn = nrm + (size_t)grow * 256 + kg;       // +4/tile

#define DEQ_TILE(WB, Q, NV)                                                     \
    do {                                                                        \
      float a2_ = (NV) * (2.0f / 3.0f);                                         \
      uint32_t tlo_ = f2bf(-(NV)) | (f2bf(fmaf(1.0f, a2_, -(NV))) << 16);       \
      uint32_t thi_ = f2bf(fmaf(2.0f, a2_, -(NV))) |                            \
                      (f2bf(fmaf(3.0f, a2_, -(NV))) << 16);                     \
      Bb[WB][bsA] = deq8((Q).x, (Q).y, tlo_, thi_);                             \
      Bb[WB][bsB] = deq8((Q).z, (Q).w, tlo_, thi_);                             \
    } while (0)

    // prologue: deq tiles 0,1; hold pairs (2,3)->E and (4,5)->O in flight
    {
      uint4 t0 = *(const uint4*)pq;         float y0 = pn[0];
      uint4 t1 = *(const uint4*)(pq + 16);  float y1 = pn[4];
      DEQ_TILE(0, t0, y0);
      DEQ_TILE(1, t1, y1);
    }
    uint4 qE0 = *(const uint4*)(pq + 32);  float nE0 = pn[8];    // tile 2
    uint4 qE1 = *(const uint4*)(pq + 48);  float nE1 = pn[12];   // tile 3
    uint4 qO0 = *(const uint4*)(pq + 64);  float nO0 = pn[16];   // tile 4
    uint4 qO1 = *(const uint4*)(pq + 80);  float nO1 = pn[20];   // tile 5
    const uint32_t* pql = pq + 96;   // tile 6; +32 words per phase
    const float*    pnl = pn + 24;
    LDS_BARRIER();

    for (int tp = 0; tp < NT; tp += 4) {
      // even phase: write tiles tp+2,tp+3 -> bufs 2,3; reload E = tp+6,tp+7
      if (tp + 2 < NT) {
        DEQ_TILE(2, qE0, nE0);
        DEQ_TILE(3, qE1, nE1);
      }
      if (tp + 6 < NT) {
        qE0 = *(const uint4*)pql;        nE0 = pnl[0];
        qE1 = *(const uint4*)(pql + 16); nE1 = pnl[4];
      }
      pql += 32; pnl += 8;
      LDS_BARRIER();
      // odd phase: write tiles tp+4,tp+5 -> bufs 0,1; reload O = tp+8,tp+9
      if (tp + 4 < NT) {
        DEQ_TILE(0, qO0, nO0);
        DEQ_TILE(1, qO1, nO1);
      }
      if (tp + 8 < NT) {
        qO0 = *(const uint4*)pql;        nO0 = pnl[0];
        qO1 = *(const uint4*)(pql + 16); nO1 = pnl[4];
      }
      pql += 32; pnl += 8;
      LDS_BARRIER();
    }
#undef DEQ_TILE
  }
}

// ---------------------------------------------------------------------------
extern "C" void kernel_launch(void* const* d_in, const int* in_sizes, int n_in,
                              void* d_out, int out_size, void* d_ws, size_t ws_size,
                              hipStream_t stream) {
  const float*    x    = (const float*)d_in[0];
  const uint32_t* q2   = (const uint32_t*)d_in[1];
  const float*    nm   = (const float*)d_in[2];
  const float*    bias = (const float*)d_in[3];
  float*          out  = (float*)d_out;
  uint4*          aws  = (uint4*)d_ws;   // 2 MiB: x as bf16 fragment chunks

  cvt_x_kernel<<<512, 256, 0, stream>>>(x, aws);
  gemm2bit_kernel<<<dim3(N_DIM / BN, 2), 512, 0, stream>>>(aws, q2, nm, bias, out);
}

// Round 12
// 154.349 us; speedup vs baseline: 1.0440x; 1.0440x over previous
//
#include <hip/hip_runtime.h>
#include <stdint.h>

// Problem: out[m][n] = sum_k x[m][k] * w[n][k] + bias[n]
//   M=256, N=16384, K=4096, w = dequant(2-bit, group=16 along k)
// Round 12: round-10 producer/consumer (62us best) with ONLY the 4-deep-ring
// change from round 11 (whose regression was the consumer-geometry A-traffic
// doubling, FETCH 53->72MB -- reverted here).
//  - consumers: 32m x 64n each (disjoint m-panels, A read once per use).
//  - 4-deep LDS tile ring (32 KiB), barrier every 2 tiles (32 barriers):
//    producers write bufs {2,3} while consumers read {0,1}, then swap.
//  - producers hold 2 tile-pairs of q2/nrm in flight (4-tile HBM lead).
// Skeleton: grid (256,2), 512 thr, BM=128/BN=64/BK=64, XOR-swizzled B LDS,
// lgkm-only barrier, A via coalesced fragment workspace, setprio around MFMA.
#define M_DIM 256
#define N_DIM 16384
#define K_DIM 4096
#define BN 64
#define BK 64
#define NT (K_DIM / BK)   // 64 k-tiles

typedef __bf16 bf16x8 __attribute__((ext_vector_type(8)));
typedef float  f32x4  __attribute__((ext_vector_type(4)));

// fp32 -> bf16 bits, round-nearest-even (finite inputs)
__device__ __forceinline__ uint32_t f2bf(float f) {
  uint32_t u = __float_as_uint(f);
  return (u + 0x7fffu + ((u >> 16) & 1u)) >> 16;
}

// Barrier that waits ONLY on LDS ops -- global prefetches stay in flight.
#define LDS_BARRIER() \
  asm volatile("s_waitcnt lgkmcnt(0)\n\ts_barrier" ::: "memory")

// ---------------------------------------------------------------------------
// Kernel 1: x fp32 [256][4096] -> bf16 fragment-chunk order (unchanged).
// Chunk = (m-block of 16 rows) x (k-chunk of 32): 64 slots x 16B.
// Slot L holds row (L&15), k = (L>>4)*8 .. +7  (MFMA 16x16x32 A-frag order).
// ws uint4 index = (mb_glob*128 + kch)*64 + L.
// ---------------------------------------------------------------------------
__global__ __launch_bounds__(256) void cvt_x_kernel(const float* __restrict__ x,
                                                    uint4* __restrict__ ws) {
  int T = blockIdx.x * 256 + threadIdx.x;       // 0..131071
  int mb_glob = T >> 13;                        // 16 m-blocks
  int r       = T & 8191;
  int kch     = r >> 6;                         // 128 k-chunks
  int L       = r & 63;
  int row = mb_glob * 16 + (L & 15);
  int k   = kch * 32 + (L >> 4) * 8;
  const float* p = x + (size_t)row * K_DIM + k;
  float4 a = *(const float4*)p;
  float4 b = *(const float4*)(p + 4);
  uint4 o;
  o.x = f2bf(a.x) | (f2bf(a.y) << 16);
  o.y = f2bf(a.z) | (f2bf(a.w) << 16);
  o.z = f2bf(b.x) | (f2bf(b.y) << 16);
  o.w = f2bf(b.z) | (f2bf(b.w) << 16);
  ws[T] = o;
}

// ---------------------------------------------------------------------------
// Dequant 8 elems (2 packed q2 words; 4 crumbs in each low byte) of one group.
// Table entries {-n, a-n, 2a-n, 3a-n}, a = n*2/3 -- bit-identical to the
// fmaf+f2bf reference path.  v_perm_b32 picks the bf16 entry per crumb.
// ---------------------------------------------------------------------------
__device__ __forceinline__ uint4 deq8(uint32_t qx, uint32_t qy, uint32_t tlo,
                                      uint32_t thi) {
  uint32_t s0 = ((qx & 3u) | ((qx & 0xCu) << 14)) * 0x0202u + 0x01000100u;
  uint32_t s1 = (((qx >> 4) & 3u) | ((qx & 0xC0u) << 10)) * 0x0202u + 0x01000100u;
  uint32_t s2 = ((qy & 3u) | ((qy & 0xCu) << 14)) * 0x0202u + 0x01000100u;
  uint32_t s3 = (((qy >> 4) & 3u) | ((qy & 0xC0u) << 10)) * 0x0202u + 0x01000100u;
  uint4 r;
  r.x = __builtin_amdgcn_perm(thi, tlo, s0);
  r.y = __builtin_amdgcn_perm(thi, tlo, s1);
  r.z = __builtin_amdgcn_perm(thi, tlo, s2);
  r.w = __builtin_amdgcn_perm(thi, tlo, s3);
  return r;
}

// ---------------------------------------------------------------------------
// Kernel 2: grid (256,2), 512 threads, 8 waves: 4 consumers + 4 producers.
// LDS: Bb[4][512] -- tile T lives in buffer T&3 (8 chunks x 64 slots each).
// ---------------------------------------------------------------------------
__global__ __launch_bounds__(512, 4) void gemm2bit_kernel(
    const uint4*    __restrict__ aws,  // A chunks (see cvt)
    const uint32_t* __restrict__ q2,   // [G][4] packed 2-bit (low byte crumbs)
    const float*    __restrict__ nrm,  // [G] group norms (f32)
    const float*    __restrict__ bias, // [N]
    float*          __restrict__ out)  // [256][16384] fp32
{
  __shared__ uint4 Bb[4][512];  // 4-deep tile ring, 32 KiB

  const int tid  = threadIdx.x;
  const int lane = tid & 63;
  const int w    = tid >> 6;    // 0..7
  const int lo4  = lane & 15;
  const int qd   = lane >> 4;
  const int n0   = blockIdx.x * BN;
  const int m0   = blockIdx.y * 128;

  if (w < 4) {
    // ================== CONSUMER wave: 32m x 64n (disjoint m) =============
    const int cw  = w;           // m-panel: rows m0 + cw*32 .. +31
    const int lrs = lane ^ qd;   // swizzled read lane

    // A frag source: m-chunks mb = blockIdx.y*8 + cw*2 + {0,1}
    const uint4* pA = aws + (size_t)(blockIdx.y * 8 + cw * 2) * 8192 + lane;

    f32x4 acc[2][4];
#pragma unroll
    for (int s = 0; s < 2; ++s)
#pragma unroll
      for (int u = 0; u < 4; ++u)
        acc[s][u] = (f32x4){0.f, 0.f, 0.f, 0.f};

    uint4 afE[4], afO[4];   // [s*2+ts] for one tile, ping-pong
#pragma unroll
    for (int s = 0; s < 2; ++s)
#pragma unroll
      for (int ts = 0; ts < 2; ++ts)
        afE[s * 2 + ts] = pA[(size_t)s * 8192 + ts * 64];
    const uint4* pAp = pA + 128;   // next tile's A (2 chunks = 128 uint4)
    LDS_BARRIER();   // matches producer prologue (tiles 0,1 written)

    // one tile: prefetch A(next), 8 ds_read B, 16 MFMA
#define CONS_TILE(BUF, AFC, AFN, TNEXT)                                         \
    do {                                                                        \
      if ((TNEXT) < NT) {                                                       \
        _Pragma("unroll")                                                       \
        for (int s = 0; s < 2; ++s)                                             \
          _Pragma("unroll")                                                     \
          for (int ts = 0; ts < 2; ++ts)                                        \
            AFN[s * 2 + ts] = pAp[(size_t)s * 8192 + ts * 64];                  \
      }                                                                         \
      pAp += 128;                                                               \
      __builtin_amdgcn_s_setprio(1);                                            \
      _Pragma("unroll")                                                         \
      for (int ts = 0; ts < 2; ++ts) {                                          \
        bf16x8 bfv[4];                                                          \
        _Pragma("unroll")                                                       \
        for (int u = 0; u < 4; ++u)                                             \
          bfv[u] = *(const bf16x8*)&Bb[BUF][(ts * 4 + u) * 64 + lrs];           \
        _Pragma("unroll")                                                       \
        for (int s = 0; s < 2; ++s) {                                           \
          bf16x8 av = __builtin_bit_cast(bf16x8, AFC[s * 2 + ts]);              \
          _Pragma("unroll")                                                     \
          for (int u = 0; u < 4; ++u)                                           \
            acc[s][u] = __builtin_amdgcn_mfma_f32_16x16x32_bf16(av, bfv[u],     \
                                                            acc[s][u], 0, 0, 0);\
        }                                                                       \
      }                                                                         \
      __builtin_amdgcn_s_setprio(0);                                            \
    } while (0)

    for (int tp = 0; tp < NT; tp += 4) {
      // phase A: tiles tp, tp+1 from bufs 0,1 (producers writing 2,3)
      CONS_TILE(0, afE, afO, tp + 1);
      CONS_TILE(1, afO, afE, tp + 2);
      LDS_BARRIER();
      // phase B: tiles tp+2, tp+3 from bufs 2,3 (producers writing 0,1)
      CONS_TILE(2, afE, afO, tp + 3);
      CONS_TILE(3, afO, afE, tp + 4);
      LDS_BARRIER();
    }
#undef CONS_TILE

    // epilogue: C/D layout col=lane&15 (n), row=(lane>>4)*4+reg (m)
    float bv[4];
#pragma unroll
    for (int u = 0; u < 4; ++u)
      bv[u] = bias[n0 + u * 16 + lo4];
#pragma unroll
    for (int s = 0; s < 2; ++s) {
      int mrow = m0 + cw * 32 + s * 16 + qd * 4;
#pragma unroll
      for (int u = 0; u < 4; ++u) {
        int ncol = n0 + u * 16 + lo4;
        float* p = out + (size_t)mrow * N_DIM + ncol;
#pragma unroll
        for (int r = 0; r < 4; ++r)
          p[(size_t)r * N_DIM] = acc[s][u][r] + bv[u];
      }
    }
  } else {
    // ================== PRODUCER wave: 16n x 4 k-groups ===================
    const int pw    = w - 4;        // n-16-block 0..3
    const int kg    = lane & 3;     // k-group within BK (0..3)
    const int n_loc = lane >> 2;    // 0..15
    const int grow  = n0 + pw * 16 + n_loc;
    const int qd2a  = (kg & 1) * 2;
    const int qd2b  = qd2a + 1;
    const int bsA = ((kg >> 1) * 4 + pw) * 64 + qd2a * 16 + (n_loc ^ qd2a);
    const int bsB = ((kg >> 1) * 4 + pw) * 64 + qd2b * 16 + (n_loc ^ qd2b);

    const uint32_t* pq = q2 + ((size_t)grow * 256 + kg) * 4;  // +16 words/tile
    const float*    pn = nrm + (size_t)grow * 256 + kg;       // +4/tile

#define DEQ_TILE(WB, Q, NV)                                                     \
    do {                                                                        \
      float a2_ = (NV) * (2.0f / 3.0f);                                         \
      uint32_t tlo_ = f2bf(-(NV)) | (f2bf(fmaf(1.0f, a2_, -(NV))) << 16);       \
      uint32_t thi_ = f2bf(fmaf(2.0f, a2_, -(NV))) |                            \
                      (f2bf(fmaf(3.0f, a2_, -(NV))) << 16);                     \
      Bb[WB][bsA] = deq8((Q).x, (Q).y, tlo_, thi_);                             \
      Bb[WB][bsB] = deq8((Q).z, (Q).w, tlo_, thi_);                             \
    } while (0)

    // prologue: deq tiles 0,1 -> bufs 0,1; hold (2,3)->E, (4,5)->O in flight
    {
      uint4 t0 = *(const uint4*)pq;         float y0 = pn[0];
      uint4 t1 = *(const uint4*)(pq + 16);  float y1 = pn[4];
      DEQ_TILE(0, t0, y0);
      DEQ_TILE(1, t1, y1);
    }
    uint4 qE0 = *(const uint4*)(pq + 32);  float nE0 = pn[8];    // tile 2
    uint4 qE1 = *(const uint4*)(pq + 48);  float nE1 = pn[12];   // tile 3
    uint4 qO0 = *(const uint4*)(pq + 64);  float nO0 = pn[16];   // tile 4
    uint4 qO1 = *(const uint4*)(pq + 80);  float nO1 = pn[20];   // tile 5
    const uint32_t* pql = pq + 96;   // tile 6; +32 words per phase
    const float*    pnl = pn + 24;
    LDS_BARRIER();

    for (int tp = 0; tp < NT; tp += 4) {
      // phase A: write tiles tp+2,tp+3 -> bufs 2,3; reload E = tp+6,tp+7
      if (tp + 2 < NT) {
        DEQ_TILE(2, qE0, nE0);
        DEQ_TILE(3, qE1, nE1);
      }
      if (tp + 6 < NT) {
        qE0 = *(const uint4*)pql;        nE0 = pnl[0];
        qE1 = *(const uint4*)(pql + 16); nE1 = pnl[4];
      }
      pql += 32; pnl += 8;
      LDS_BARRIER();
      // phase B: write tiles tp+4,tp+5 -> bufs 0,1; reload O = tp+8,tp+9
      if (tp + 4 < NT) {
        DEQ_TILE(0, qO0, nO0);
        DEQ_TILE(1, qO1, nO1);
      }
      if (tp + 8 < NT) {
        qO0 = *(const uint4*)pql;        nO0 = pnl[0];
        qO1 = *(const uint4*)(pql + 16); nO1 = pnl[4];
      }
      pql += 32; pnl += 8;
      LDS_BARRIER();
    }
#undef DEQ_TILE
  }
}

// ---------------------------------------------------------------------------
extern "C" void kernel_launch(void* const* d_in, const int* in_sizes, int n_in,
                              void* d_out, int out_size, void* d_ws, size_t ws_size,
                              hipStream_t stream) {
  const float*    x    = (const float*)d_in[0];
  const uint32_t* q2   = (const uint32_t*)d_in[1];
  const float*    nm   = (const float*)d_in[2];
  const float*    bias = (const float*)d_in[3];
  float*          out  = (float*)d_out;
  uint4*          aws  = (uint4*)d_ws;   // 2 MiB: x as bf16 fragment chunks

  cvt_x_kernel<<<512, 256, 0, stream>>>(x, aws);
  gemm2bit_kernel<<<dim3(N_DIM / BN, 2), 512, 0, stream>>>(aws, q2, nm, bias, out);
}